// Round 11
// baseline (139.098 us; speedup 1.0000x reference)
//
#include <hip/hip_runtime.h>
#include <stdint.h>

#define N_RAYS  16384
#define T_STEPS 128
#define RPW   16            // rays per wave (= per block)
#define WAVES 8             // waves per block; wave w owns t in [16w, 16w+16)
#define TSEG  16

typedef _Float16 half8  __attribute__((ext_vector_type(8)));
typedef __fp16   fp16x2 __attribute__((ext_vector_type(2)));
typedef float    float4_ __attribute__((ext_vector_type(4)));
typedef uint32_t uint2_  __attribute__((ext_vector_type(2)));

// ws layout (half8 units): W1 [0,256), FUSED [256,896), WC2 [896,1024)
#define H8_W1    0
#define H8_FUSED 256
#define H8_WC2   896
// f32 region starts at float index 4096 (byte 16384)
#define F32_CV   4096        // 5 x 64: Wc1 rows 15,16,17,18 then cconst
#define F32_BC2  4416        // 16 floats (bc2 padded)
#define F32_S0   4432        // b2[0]

__device__ __forceinline__ uint32_t pk(float a, float b) {
    fp16x2 h = __builtin_amdgcn_cvt_pkrtz(a, b);
    return __builtin_bit_cast(uint32_t, h);
}
// pack two floats -> f16x2 dword, then packed relu (v_pk_max_f16)
__device__ __forceinline__ uint32_t pkr(float a, float b) {
    fp16x2 h = __builtin_amdgcn_cvt_pkrtz(a, b);
    fp16x2 z = {(__fp16)0.f, (__fp16)0.f};
    fp16x2 m = __builtin_elementwise_max(h, z);
    return __builtin_bit_cast(uint32_t, m);
}

// ---------------------------------------------------------------------------
// prep: W1 tiles as before; W2/Wc1 fused into a 65x64 matrix (rows 0..63 = hc
// pre-activation, row 64 = sigma logit); Wc2 tiles; per-ray-constant tables.
// 16 blocks x 64 threads; block == fragment group.
// ---------------------------------------------------------------------------
__global__ void prep_weights(const float* __restrict__ W1, const float* __restrict__ b1,
                             const float* __restrict__ W2, const float* __restrict__ b2,
                             const float* __restrict__ Wc1, const float* __restrict__ bc1,
                             const float* __restrict__ Wc2, const float* __restrict__ bc2,
                             void* __restrict__ ws) {
    _Float16* wh = (_Float16*)ws;
    float*    wf = (float*)ws;
    int frag = blockIdx.x;
    int lane = threadIdx.x;
    int mm = lane & 15, q = lane >> 4;
    if (frag < 4) {                       // W1^T tiles (enc-permuted, bias folded)
        int tau = frag;
        int n = tau * 16 + mm;
        for (int j = 0; j < 8; ++j) {
            float w;
            if (j < 6)      w = W1[(3 + 6 * q + j) * 64 + n];
            else if (j == 6) w = (q == 0) ? W1[0 * 64 + n] : (q == 1) ? W1[2 * 64 + n] : 0.f;
            else             w = (q == 0) ? W1[1 * 64 + n] : (q == 1) ? b1[n] : 0.f;
            wh[(H8_W1 + tau * 64 + lane) * 8 + j] = (_Float16)w;
        }
    } else if (frag < 14) {               // fused W2[:,1:]@Wc1[:15] + sigma row
        int f = frag - 4;
        int tau = f >> 1, kap = f & 1;
        int n_out = tau * 16 + mm;        // 0..79
        for (int j = 0; j < 8; ++j) {
            int k = kap * 32 + q * 8 + j; // h index 0..63
            float w = 0.f;
            if (n_out < 64) {
                for (int c = 0; c < 15; ++c)
                    w += W2[k * 16 + 1 + c] * Wc1[c * 64 + n_out];
            } else if (n_out == 64) {
                w = W2[k * 16 + 0];
            }
            wh[(H8_FUSED + f * 64 + lane) * 8 + j] = (_Float16)w;
        }
    } else {                              // Wc2^T tiles
        int kap = frag - 14;
        for (int j = 0; j < 8; ++j) {
            int k = kap * 32 + q * 8 + j;
            wh[(H8_WC2 + kap * 64 + lane) * 8 + j] =
                (_Float16)((mm < 3) ? Wc2[k * 3 + mm] : 0.f);
        }
        if (frag == 15) {                 // per-ray-constant tables (f32)
            int n = lane;                 // 0..63
            wf[F32_CV + 0 * 64 + n] = Wc1[15 * 64 + n];
            wf[F32_CV + 1 * 64 + n] = Wc1[16 * 64 + n];
            wf[F32_CV + 2 * 64 + n] = Wc1[17 * 64 + n];
            wf[F32_CV + 3 * 64 + n] = Wc1[18 * 64 + n];
            float cc = bc1[n];
            for (int c = 0; c < 15; ++c) cc += b2[1 + c] * Wc1[c * 64 + n];
            wf[F32_CV + 4 * 64 + n] = cc;
            if (lane < 16) wf[F32_BC2 + lane] = (lane < 3) ? bc2[lane] : 0.f;
            if (lane == 0) wf[F32_S0] = b2[0];
        }
    }
}

// ---------------------------------------------------------------------------
// render: 2-deep pipeline, TWO LDS hops per sample (H after L1-relu, HC after
// fused-relu). Fused MFMA's C-initializer carries all per-ray constants.
// ---------------------------------------------------------------------------
__global__ __launch_bounds__(512, 3)
void render_kernel(const float* __restrict__ rays_o, const float* __restrict__ rays_d,
                   const float* __restrict__ tnoise, const float* __restrict__ aabb,
                   const void* __restrict__ ws, float* __restrict__ out) {
    __shared__ __align__(16) _Float16 sH[WAVES][2][1024];   // 2 KB per buf
    __shared__ float sComb[WAVES][RPW][5];

    const int tid  = threadIdx.x;
    const int wv   = tid >> 6;
    const int lane = tid & 63;
    const int m    = lane & 15;       // ray within block / sample col
    const int q    = lane >> 4;       // quad = K-chunk / freq group
    const int r    = blockIdx.x * RPW + m;

    // weight fragments -> registers
    const half8* wsv = (const half8*)ws;
    const float* wsf = (const float*)ws;
    half8 fW1[4], fF[10], fWc2[2];
    #pragma unroll
    for (int i = 0; i < 4; ++i)  fW1[i]  = wsv[H8_W1    + i * 64 + lane];
    #pragma unroll
    for (int i = 0; i < 10; ++i) fF[i]   = wsv[H8_FUSED + i * 64 + lane];
    #pragma unroll
    for (int i = 0; i < 2; ++i)  fWc2[i] = wsv[H8_WC2   + i * 64 + lane];
    const float4_ binit = ((const float4_*)(wsf + F32_BC2))[q];
    const float s0b = wsf[F32_S0];

    // per-ray setup
    float o0 = rays_o[r * 3 + 0], o1 = rays_o[r * 3 + 1], o2 = rays_o[r * 3 + 2];
    float d0 = rays_d[r * 3 + 0], d1 = rays_d[r * 3 + 1], d2 = rays_d[r * 3 + 2];
    float a00 = aabb[0], a01 = aabb[1], a02 = aabb[2];
    float a10 = aabb[3], a11 = aabb[4], a12 = aabb[5];

    float i0 = 1.0f / d0, i1 = 1.0f / d1, i2 = 1.0f / d2;
    float u0 = (a00 - o0) * i0, v0 = (a10 - o0) * i0;
    float u1 = (a01 - o1) * i1, v1 = (a11 - o1) * i1;
    float u2 = (a02 - o2) * i2, v2 = (a12 - o2) * i2;
    float tnear = fmaxf(fmaxf(fmaxf(fminf(u0, v0), fminf(u1, v1)), fminf(u2, v2)), 0.0f);
    float tfar  = fminf(fminf(fmaxf(u0, v0), fmaxf(u1, v1)), fmaxf(u2, v2));
    bool active = (tfar > tnear);
    float dt = tfar - tnear;
    float dt128 = dt * (1.0f / 128.0f);

    float dn  = sqrtf(d0 * d0 + d1 * d1 + d2 * d2);
    float idn = 1.0f / dn;
    const float c0sh = 0.28209479177387814f;
    const float c1sh = 0.4886025119029199f;
    float y1 = c1sh * d1 * idn, y2 = c1sh * d2 * idn, y3 = c1sh * d0 * idn;

    // fused-layer C-initializer: cvec[n] = cconst[n] + c0*W15[n] + y.W16..18[n]
    float4_ cv[4];
    #pragma unroll
    for (int tau = 0; tau < 4; ++tau) {
        #pragma unroll
        for (int reg = 0; reg < 4; ++reg) {
            int n = tau * 16 + 4 * q + reg;
            float c = wsf[F32_CV + 4 * 64 + n];
            c = fmaf(c0sh, wsf[F32_CV + 0 * 64 + n], c);
            c = fmaf(y1,   wsf[F32_CV + 1 * 64 + n], c);
            c = fmaf(y2,   wsf[F32_CV + 2 * 64 + n], c);
            c = fmaf(y3,   wsf[F32_CV + 3 * 64 + n], c);
            cv[tau][reg] = c;
        }
    }
    const float4_ c4init = {s0b, s0b, s0b, s0b};

    // xn in revolutions domain: r_q = 2^(q-1) * xn
    float qs = 0.5f * (float)(1 << q);
    float sc0 = 2.0f / (a10 - a00), of0 = -a00 * sc0 - 1.0f;
    float sc1 = 2.0f / (a11 - a01), of1 = -a01 * sc1 - 1.0f;
    float sc2 = 2.0f / (a12 - a02), of2 = -a02 * sc2 - 1.0f;
    float scq0 = sc0 * qs, ofq0 = of0 * qs;
    float scq1 = sc1 * qs, ofq1 = of1 * qs;
    float scq2 = sc2 * qs, ofq2 = of2 * qs;

    // loop-invariant LDS addresses, per phase
    _Float16*       hwp[2];
    const _Float16* hrp[2];
    #pragma unroll
    for (int p = 0; p < 2; ++p) {
        hwp[p] = &sH[wv][p][((q >> 1) * 16 + m) * 8 + 4 * (q & 1)];  // + tau*256
        hrp[p] = &sH[wv][p][(q * 16 + m) * 8];                       // + kap*512
    }

    const float4_ z4 = {0.f, 0.f, 0.f, 0.f};
    const bool q0 = (q == 0), q1 = (q == 1);

    float trans = 1.0f, sdtot = 0.0f, wacc = 0.0f;
    float cacc0 = 0.0f, cacc1 = 0.0f, cacc2 = 0.0f;

    const int tbase = wv * TSEG;
    float nA = tnoise[(tbase + 0) * N_RAYS + r];
    float nB = tnoise[(tbase + 1) * N_RAYS + r];

    #pragma unroll 1
    for (int tt = 0; tt < TSEG; tt += 2) {
        const int t0 = tbase + tt, t1 = t0 + 1;
        float nC = (t0 + 2 < T_STEPS) ? tnoise[(t0 + 2) * N_RAYS + r] : 0.0f;
        float nD = (t0 + 3 < T_STEPS) ? tnoise[(t0 + 3) * N_RAYS + r] : 0.0f;
        float ts0 = fmaf((float)t0 + nA, dt128, tnear);
        float ts1 = fmaf((float)t1 + nB, dt128, tnear);
        float ts2 = fmaf((float)(t0 + 2) + nC, dt128, tnear);
        float tsP[2] = {ts0, ts1};
        float deltaP[2];
        deltaP[0] = ts1 - ts0;
        deltaP[1] = (t1 < T_STEPS - 1) ? (ts2 - ts1) : fmaf(tfar, 10.0f, -ts1);
        nA = nC; nB = nD;

        float dhx[2];
        float4_ rgbP[2];

        // ---- FRONT (both phases): posenc -> L1 -> relu/pack -> write H[p] ----
        #pragma unroll
        for (int p = 0; p < 2; ++p) {
            float x = fmaf(tsP[p], d0, o0);
            float y = fmaf(tsP[p], d1, o1);
            float z = fmaf(tsP[p], d2, o2);
            float xr0 = fmaf(x, scq0, ofq0);
            float xr1 = fmaf(y, scq1, ofq1);
            float xr2 = fmaf(z, scq2, ofq2);
            float s0 = __builtin_amdgcn_sinf(xr0);
            float s1 = __builtin_amdgcn_sinf(xr1);
            float s2 = __builtin_amdgcn_sinf(xr2);
            float cA = __builtin_amdgcn_cosf(xr0);
            float cB = __builtin_amdgcn_cosf(xr1);
            float cC = __builtin_amdgcn_cosf(xr2);
            float e6 = q0 ? (xr0 + xr0) : (q1 ? xr2 : 0.0f);
            float e7 = q0 ? (xr1 + xr1) : (q1 ? 1.0f : 0.0f);
            union { uint32_t u[4]; half8 h; } xf_;
            xf_.u[0] = pk(s0, s1); xf_.u[1] = pk(s2, cA);
            xf_.u[2] = pk(cB, cC); xf_.u[3] = pk(e6, e7);
            half8 xf = xf_.h;

            float4_ h0 = __builtin_amdgcn_mfma_f32_16x16x32_f16(fW1[0], xf, z4, 0, 0, 0);
            float4_ h1 = __builtin_amdgcn_mfma_f32_16x16x32_f16(fW1[1], xf, z4, 0, 0, 0);
            float4_ h2 = __builtin_amdgcn_mfma_f32_16x16x32_f16(fW1[2], xf, z4, 0, 0, 0);
            float4_ h3 = __builtin_amdgcn_mfma_f32_16x16x32_f16(fW1[3], xf, z4, 0, 0, 0);
            uint2_ w;
            w.x = pkr(h0.x, h0.y); w.y = pkr(h0.z, h0.w); *(uint2_*)(hwp[p] + 0 * 256) = w;
            w.x = pkr(h1.x, h1.y); w.y = pkr(h1.z, h1.w); *(uint2_*)(hwp[p] + 1 * 256) = w;
            w.x = pkr(h2.x, h2.y); w.y = pkr(h2.z, h2.w); *(uint2_*)(hwp[p] + 2 * 256) = w;
            w.x = pkr(h3.x, h3.y); w.y = pkr(h3.z, h3.w); *(uint2_*)(hwp[p] + 3 * 256) = w;
        }

        // ---- MID: read H[p] -> FUSED (hc pre-act + sigma row) -> write HC[p] ----
        #pragma unroll
        for (int p = 0; p < 2; ++p) {
            half8 hb0 = *(const half8*)(hrp[p] + 0);
            half8 hb1 = *(const half8*)(hrp[p] + 512);
            float4_ d4 = __builtin_amdgcn_mfma_f32_16x16x32_f16(fF[8], hb0, c4init, 0, 0, 0);
            d4 = __builtin_amdgcn_mfma_f32_16x16x32_f16(fF[9], hb1, d4, 0, 0, 0);
            dhx[p] = d4.x;   // sigma logit, valid on q==0 lanes
            float4_ t0v = __builtin_amdgcn_mfma_f32_16x16x32_f16(fF[0], hb0, cv[0], 0, 0, 0);
            t0v = __builtin_amdgcn_mfma_f32_16x16x32_f16(fF[1], hb1, t0v, 0, 0, 0);
            float4_ t1v = __builtin_amdgcn_mfma_f32_16x16x32_f16(fF[2], hb0, cv[1], 0, 0, 0);
            t1v = __builtin_amdgcn_mfma_f32_16x16x32_f16(fF[3], hb1, t1v, 0, 0, 0);
            float4_ t2v = __builtin_amdgcn_mfma_f32_16x16x32_f16(fF[4], hb0, cv[2], 0, 0, 0);
            t2v = __builtin_amdgcn_mfma_f32_16x16x32_f16(fF[5], hb1, t2v, 0, 0, 0);
            float4_ t3v = __builtin_amdgcn_mfma_f32_16x16x32_f16(fF[6], hb0, cv[3], 0, 0, 0);
            t3v = __builtin_amdgcn_mfma_f32_16x16x32_f16(fF[7], hb1, t3v, 0, 0, 0);
            uint2_ w;
            w.x = pkr(t0v.x, t0v.y); w.y = pkr(t0v.z, t0v.w); *(uint2_*)(hwp[p] + 0 * 256) = w;
            w.x = pkr(t1v.x, t1v.y); w.y = pkr(t1v.z, t1v.w); *(uint2_*)(hwp[p] + 1 * 256) = w;
            w.x = pkr(t2v.x, t2v.y); w.y = pkr(t2v.z, t2v.w); *(uint2_*)(hwp[p] + 2 * 256) = w;
            w.x = pkr(t3v.x, t3v.y); w.y = pkr(t3v.z, t3v.w); *(uint2_*)(hwp[p] + 3 * 256) = w;
        }

        // ---- FIN: read HC[p] -> C2 -> rgb logits ----
        #pragma unroll
        for (int p = 0; p < 2; ++p) {
            half8 cb0 = *(const half8*)(hrp[p] + 0);
            half8 cb1 = *(const half8*)(hrp[p] + 512);
            float4_ rgbp = __builtin_amdgcn_mfma_f32_16x16x32_f16(fWc2[0], cb0, binit, 0, 0, 0);
            rgbP[p] = __builtin_amdgcn_mfma_f32_16x16x32_f16(fWc2[1], cb1, rgbp, 0, 0, 0);
        }

        // ---- TAIL (q==0 lanes): sequential volume-rendering scan ----
        if (q == 0) {
            #pragma unroll
            for (int p = 0; p < 2; ++p) {
                float sigma = __expf(dhx[p]);
                float sd = sigma * deltaP[p] * dn;
                float e = __expf(-sd);
                float alpha = 1.0f - e;
                float w = trans * alpha;
                float rr = __builtin_amdgcn_rcpf(1.0f + __expf(-rgbP[p].x));
                float rg = __builtin_amdgcn_rcpf(1.0f + __expf(-rgbP[p].y));
                float rb = __builtin_amdgcn_rcpf(1.0f + __expf(-rgbP[p].z));
                cacc0 = fmaf(w, rr, cacc0);
                cacc1 = fmaf(w, rg, cacc1);
                cacc2 = fmaf(w, rb, cacc2);
                wacc += w;
                trans *= e;
                sdtot += sd;
            }
        }
    }

    if (q == 0) {
        sComb[wv][m][0] = sdtot;
        sComb[wv][m][1] = wacc;
        sComb[wv][m][2] = cacc0;
        sComb[wv][m][3] = cacc1;
        sComb[wv][m][4] = cacc2;
    }
    __syncthreads();

    // cross-segment combine
    if (tid < RPW) {
        float P = 1.0f, C0 = 0.0f, C1 = 0.0f, C2 = 0.0f, WS = 0.0f;
        #pragma unroll
        for (int s = 0; s < WAVES; ++s) {
            C0 = fmaf(P, sComb[s][tid][2], C0);
            C1 = fmaf(P, sComb[s][tid][3], C1);
            C2 = fmaf(P, sComb[s][tid][4], C2);
            WS = fmaf(P, sComb[s][tid][1], WS);
            P *= __expf(-sComb[s][tid][0]);
        }
        float act = active ? 1.0f : 0.0f;
        const int rg = blockIdx.x * RPW + tid;
        out[rg * 4 + 0] = C0 * act;
        out[rg * 4 + 1] = C1 * act;
        out[rg * 4 + 2] = C2 * act;
        out[rg * 4 + 3] = WS * act;
    }
}

extern "C" void kernel_launch(void* const* d_in, const int* in_sizes, int n_in,
                              void* d_out, int out_size, void* d_ws, size_t ws_size,
                              hipStream_t stream) {
    const float* rays_o = (const float*)d_in[0];
    const float* rays_d = (const float*)d_in[1];
    const float* tnoise = (const float*)d_in[2];
    const float* aabb   = (const float*)d_in[3];
    const float* W1  = (const float*)d_in[4];
    const float* b1  = (const float*)d_in[5];
    const float* W2  = (const float*)d_in[6];
    const float* b2  = (const float*)d_in[7];
    const float* Wc1 = (const float*)d_in[8];
    const float* bc1 = (const float*)d_in[9];
    const float* Wc2 = (const float*)d_in[10];
    const float* bc2 = (const float*)d_in[11];

    prep_weights<<<dim3(16), dim3(64), 0, stream>>>(W1, b1, W2, b2, Wc1, bc1, Wc2, bc2, d_ws);

    dim3 grid(N_RAYS / RPW);   // 1024 blocks
    dim3 block(WAVES * 64);    // 512 threads
    render_kernel<<<grid, block, 0, stream>>>(rays_o, rays_d, tnoise, aabb, d_ws,
                                              (float*)d_out);
}

// Round 13
// 120.924 us; speedup vs baseline: 1.1503x; 1.1503x over previous
//
#include <hip/hip_runtime.h>
#include <stdint.h>

#define N_RAYS  16384
#define T_STEPS 128
#define RPW   16            // rays per wave (= per block)
#define WAVES 4             // waves per block; wave w owns t in [32w, 32w+32)
#define TSEG  32

typedef _Float16 half8  __attribute__((ext_vector_type(8)));
typedef _Float16 half4  __attribute__((ext_vector_type(4)));
typedef __fp16   fp16x2 __attribute__((ext_vector_type(2)));
typedef float    float4_ __attribute__((ext_vector_type(4)));
typedef uint32_t uint2_  __attribute__((ext_vector_type(2)));

// ws layout, half indices: W1 tiles [0,2048), W2 [2048,3072), WC2 [3072,4096),
// WC1-K16 half4 tiles [4096,5120). f32 region at float index 3072 (byte 12288).
#define H8_W1    0
#define H8_W2    256
#define H8_WC2   384
#define H_WC1K16 4096
#define F32_CV   3072        // 5 x 64: Wc1 rows 15,16,17,18 then cconst
#define F32_BC2  3392        // 16 floats (bc2 padded)
#define F32_S0   3408        // b2[0]

__device__ __forceinline__ uint32_t pk(float a, float b) {
    fp16x2 h = __builtin_amdgcn_cvt_pkrtz(a, b);
    return __builtin_bit_cast(uint32_t, h);
}
// pack two floats -> f16x2 dword, then packed relu (v_pk_max_f16)
__device__ __forceinline__ uint32_t pkr(float a, float b) {
    fp16x2 h = __builtin_amdgcn_cvt_pkrtz(a, b);
    fp16x2 z = {(__fp16)0.f, (__fp16)0.f};
    fp16x2 m = __builtin_elementwise_max(h, z);
    return __builtin_bit_cast(uint32_t, m);
}

// ---------------------------------------------------------------------------
// prep. 13 blocks x 64 threads; blockIdx = fragment group.
// ---------------------------------------------------------------------------
__global__ void prep_weights(const float* __restrict__ W1, const float* __restrict__ b1,
                             const float* __restrict__ W2, const float* __restrict__ b2,
                             const float* __restrict__ Wc1, const float* __restrict__ bc1,
                             const float* __restrict__ Wc2, const float* __restrict__ bc2,
                             void* __restrict__ ws) {
    _Float16* wh = (_Float16*)ws;
    float*    wf = (float*)ws;
    int frag = blockIdx.x;
    int lane = threadIdx.x;
    int mm = lane & 15, q = lane >> 4;
    if (frag < 4) {                       // W1^T tiles (enc-permuted, b1 folded)
        int tau = frag;
        int n = tau * 16 + mm;
        for (int j = 0; j < 8; ++j) {
            float w;
            if (j < 6)      w = W1[(3 + 6 * q + j) * 64 + n];
            else if (j == 6) w = (q == 0) ? W1[0 * 64 + n] : (q == 1) ? W1[2 * 64 + n] : 0.f;
            else             w = (q == 0) ? W1[1 * 64 + n] : (q == 1) ? b1[n] : 0.f;
            wh[(H8_W1 + tau * 64 + lane) * 8 + j] = (_Float16)w;
        }
    } else if (frag < 6) {                // W2^T (rows = dh, row0 = sigma logit)
        int kap = frag - 4;
        for (int j = 0; j < 8; ++j) {
            int k = kap * 32 + q * 8 + j;
            wh[(H8_W2 + kap * 64 + lane) * 8 + j] = (_Float16)W2[k * 16 + mm];
        }
    } else if (frag < 10) {               // Wc1 as K=16 A-frag tiles (half4/lane)
        int tau = frag - 6;               // A[n'][k], n' = 16 tau + mm, k = 4q + j
        int n2 = tau * 16 + mm;
        for (int j = 0; j < 4; ++j) {
            int k = 4 * q + j;            // k=0 -> sigma slot, dead weight
            float w = (k == 0) ? 0.f : Wc1[(k - 1) * 64 + n2];
            wh[H_WC1K16 + (tau * 64 + lane) * 4 + j] = (_Float16)w;
        }
    } else if (frag < 12) {               // Wc2^T tiles
        int kap = frag - 10;
        for (int j = 0; j < 8; ++j) {
            int k = kap * 32 + q * 8 + j;
            wh[(H8_WC2 + kap * 64 + lane) * 8 + j] =
                (_Float16)((mm < 3) ? Wc2[k * 3 + mm] : 0.f);
        }
    } else {                              // f32 constant tables
        int n = lane;
        wf[F32_CV + 0 * 64 + n] = Wc1[15 * 64 + n];
        wf[F32_CV + 1 * 64 + n] = Wc1[16 * 64 + n];
        wf[F32_CV + 2 * 64 + n] = Wc1[17 * 64 + n];
        wf[F32_CV + 3 * 64 + n] = Wc1[18 * 64 + n];
        float cc = bc1[n];
        for (int c = 0; c < 15; ++c) cc += b2[1 + c] * Wc1[c * 64 + n];
        wf[F32_CV + 4 * 64 + n] = cc;
        if (lane < 16) wf[F32_BC2 + lane] = (lane < 3) ? bc2[lane] : 0.f;
        if (lane == 0) wf[F32_S0] = b2[0];
    }
}

// ---------------------------------------------------------------------------
// render: 2-deep pipeline; TWO LDS hops per sample (H, HC). The dh->C1
// transition is in-register: 16x16x16 MFMA B-frag layout == C/D layout.
// ---------------------------------------------------------------------------
__global__ __launch_bounds__(256, 4)
void render_kernel(const float* __restrict__ rays_o, const float* __restrict__ rays_d,
                   const float* __restrict__ tnoise, const float* __restrict__ aabb,
                   const void* __restrict__ ws, float* __restrict__ out) {
    __shared__ __align__(16) _Float16 sH[WAVES][2][1024];   // 2 KB per buf
    __shared__ float sComb[WAVES][RPW][5];

    const int tid  = threadIdx.x;
    const int wv   = tid >> 6;
    const int lane = tid & 63;
    const int m    = lane & 15;       // ray within block / sample col
    const int q    = lane >> 4;       // quad
    const int r    = blockIdx.x * RPW + m;

    // weight fragments -> registers (40 VGPRs)
    const half8* wsv  = (const half8*)ws;
    const half4* wsv4 = (const half4*)((const _Float16*)ws + H_WC1K16);
    const float* wsf  = (const float*)ws;
    half8 fW1[4], fW2[2], fWc2[2];
    half4 fWc1[4];
    #pragma unroll
    for (int i = 0; i < 4; ++i) fW1[i]  = wsv[H8_W1  + i * 64 + lane];
    #pragma unroll
    for (int i = 0; i < 2; ++i) fW2[i]  = wsv[H8_W2  + i * 64 + lane];
    #pragma unroll
    for (int i = 0; i < 2; ++i) fWc2[i] = wsv[H8_WC2 + i * 64 + lane];
    #pragma unroll
    for (int i = 0; i < 4; ++i) fWc1[i] = wsv4[i * 64 + lane];
    const float4_ binit = ((const float4_*)(wsf + F32_BC2))[q];
    const float s0b = wsf[F32_S0];

    // per-ray setup
    float o0 = rays_o[r * 3 + 0], o1 = rays_o[r * 3 + 1], o2 = rays_o[r * 3 + 2];
    float d0 = rays_d[r * 3 + 0], d1 = rays_d[r * 3 + 1], d2 = rays_d[r * 3 + 2];
    float a00 = aabb[0], a01 = aabb[1], a02 = aabb[2];
    float a10 = aabb[3], a11 = aabb[4], a12 = aabb[5];

    float i0 = 1.0f / d0, i1 = 1.0f / d1, i2 = 1.0f / d2;
    float u0 = (a00 - o0) * i0, v0 = (a10 - o0) * i0;
    float u1 = (a01 - o1) * i1, v1 = (a11 - o1) * i1;
    float u2 = (a02 - o2) * i2, v2 = (a12 - o2) * i2;
    float tnear = fmaxf(fmaxf(fmaxf(fminf(u0, v0), fminf(u1, v1)), fminf(u2, v2)), 0.0f);
    float tfar  = fminf(fminf(fmaxf(u0, v0), fmaxf(u1, v1)), fmaxf(u2, v2));
    bool active = (tfar > tnear);
    float dt = tfar - tnear;
    float dt128 = dt * (1.0f / 128.0f);

    float dn  = sqrtf(d0 * d0 + d1 * d1 + d2 * d2);
    float idn = 1.0f / dn;
    const float c0sh = 0.28209479177387814f;
    const float c1sh = 0.4886025119029199f;
    float y1 = c1sh * d1 * idn, y2 = c1sh * d2 * idn, y3 = c1sh * d0 * idn;

    // C1 C-initializer (per-ray): cv[n] = cconst[n] + c0*W15[n] + y.W16..18[n]
    float4_ cv[4];
    #pragma unroll
    for (int tau = 0; tau < 4; ++tau) {
        #pragma unroll
        for (int reg = 0; reg < 4; ++reg) {
            int n = tau * 16 + 4 * q + reg;
            float c = wsf[F32_CV + 4 * 64 + n];
            c = fmaf(c0sh, wsf[F32_CV + 0 * 64 + n], c);
            c = fmaf(y1,   wsf[F32_CV + 1 * 64 + n], c);
            c = fmaf(y2,   wsf[F32_CV + 2 * 64 + n], c);
            c = fmaf(y3,   wsf[F32_CV + 3 * 64 + n], c);
            cv[tau][reg] = c;
        }
    }

    // xn in revolutions domain: r_q = 2^(q-1) * xn
    float qs = 0.5f * (float)(1 << q);
    float sc0 = 2.0f / (a10 - a00), of0 = -a00 * sc0 - 1.0f;
    float sc1 = 2.0f / (a11 - a01), of1 = -a01 * sc1 - 1.0f;
    float sc2 = 2.0f / (a12 - a02), of2 = -a02 * sc2 - 1.0f;
    float scq0 = sc0 * qs, ofq0 = of0 * qs;
    float scq1 = sc1 * qs, ofq1 = of1 * qs;
    float scq2 = sc2 * qs, ofq2 = of2 * qs;

    // loop-invariant LDS addresses, per phase
    _Float16*       hwp[2];
    const _Float16* hrp[2];
    #pragma unroll
    for (int p = 0; p < 2; ++p) {
        hwp[p] = &sH[wv][p][((q >> 1) * 16 + m) * 8 + 4 * (q & 1)];  // + tau*256
        hrp[p] = &sH[wv][p][(q * 16 + m) * 8];                       // + kap*512
    }

    const float4_ z4 = {0.f, 0.f, 0.f, 0.f};
    const bool q0 = (q == 0), q1 = (q == 1);

    float trans = 1.0f, sdtot = 0.0f, wacc = 0.0f;
    float cacc0 = 0.0f, cacc1 = 0.0f, cacc2 = 0.0f;

    const int tbase = wv * TSEG;
    float nA = tnoise[(tbase + 0) * N_RAYS + r];
    float nB = tnoise[(tbase + 1) * N_RAYS + r];

    #pragma unroll 1
    for (int tt = 0; tt < TSEG; tt += 2) {
        const int t0 = tbase + tt, t1 = t0 + 1;
        float nC = (t0 + 2 < T_STEPS) ? tnoise[(t0 + 2) * N_RAYS + r] : 0.0f;
        float nD = (t0 + 3 < T_STEPS) ? tnoise[(t0 + 3) * N_RAYS + r] : 0.0f;
        float ts0 = fmaf((float)t0 + nA, dt128, tnear);
        float ts1 = fmaf((float)t1 + nB, dt128, tnear);
        float ts2 = fmaf((float)(t0 + 2) + nC, dt128, tnear);
        float tsP[2] = {ts0, ts1};
        float deltaP[2];
        deltaP[0] = ts1 - ts0;
        deltaP[1] = (t1 < T_STEPS - 1) ? (ts2 - ts1) : fmaf(tfar, 10.0f, -ts1);
        nA = nC; nB = nD;

        float dhx[2];
        float4_ rgbP[2];

        // ---- FRONT (both phases): posenc -> L1 -> relu/pack -> write H[p] ----
        #pragma unroll
        for (int p = 0; p < 2; ++p) {
            float x = fmaf(tsP[p], d0, o0);
            float y = fmaf(tsP[p], d1, o1);
            float z = fmaf(tsP[p], d2, o2);
            float xr0 = fmaf(x, scq0, ofq0);
            float xr1 = fmaf(y, scq1, ofq1);
            float xr2 = fmaf(z, scq2, ofq2);
            float s0 = __builtin_amdgcn_sinf(xr0);
            float s1 = __builtin_amdgcn_sinf(xr1);
            float s2 = __builtin_amdgcn_sinf(xr2);
            float cA = __builtin_amdgcn_cosf(xr0);
            float cB = __builtin_amdgcn_cosf(xr1);
            float cC = __builtin_amdgcn_cosf(xr2);
            float e6 = q0 ? (xr0 + xr0) : (q1 ? xr2 : 0.0f);
            float e7 = q0 ? (xr1 + xr1) : (q1 ? 1.0f : 0.0f);
            union { uint32_t u[4]; half8 h; } xf_;
            xf_.u[0] = pk(s0, s1); xf_.u[1] = pk(s2, cA);
            xf_.u[2] = pk(cB, cC); xf_.u[3] = pk(e6, e7);
            half8 xf = xf_.h;

            float4_ h0 = __builtin_amdgcn_mfma_f32_16x16x32_f16(fW1[0], xf, z4, 0, 0, 0);
            float4_ h1 = __builtin_amdgcn_mfma_f32_16x16x32_f16(fW1[1], xf, z4, 0, 0, 0);
            float4_ h2 = __builtin_amdgcn_mfma_f32_16x16x32_f16(fW1[2], xf, z4, 0, 0, 0);
            float4_ h3 = __builtin_amdgcn_mfma_f32_16x16x32_f16(fW1[3], xf, z4, 0, 0, 0);
            uint2_ w;
            w.x = pkr(h0.x, h0.y); w.y = pkr(h0.z, h0.w); *(uint2_*)(hwp[p] + 0 * 256) = w;
            w.x = pkr(h1.x, h1.y); w.y = pkr(h1.z, h1.w); *(uint2_*)(hwp[p] + 1 * 256) = w;
            w.x = pkr(h2.x, h2.y); w.y = pkr(h2.z, h2.w); *(uint2_*)(hwp[p] + 2 * 256) = w;
            w.x = pkr(h3.x, h3.y); w.y = pkr(h3.z, h3.w); *(uint2_*)(hwp[p] + 3 * 256) = w;
        }

        // ---- MID: read H[p] -> L2 (dh) -> in-register B-frag -> C1 -> HC[p] ----
        #pragma unroll
        for (int p = 0; p < 2; ++p) {
            half8 hb0 = *(const half8*)(hrp[p] + 0);
            half8 hb1 = *(const half8*)(hrp[p] + 512);
            float4_ dh = __builtin_amdgcn_mfma_f32_16x16x32_f16(fW2[0], hb0, z4, 0, 0, 0);
            dh = __builtin_amdgcn_mfma_f32_16x16x32_f16(fW2[1], hb1, dh, 0, 0, 0);
            dhx[p] = dh.x;   // sigma logit on q==0 lanes

            // dh C-layout (row=4q+reg) == 16x16x16 B-layout (k=4q+j): no LDS hop
            union { uint32_t u[2]; half4 h; } bf_;
            bf_.u[0] = pk(dh.x, dh.y); bf_.u[1] = pk(dh.z, dh.w);
            half4 fb = bf_.h;

            float4_ t0v = __builtin_amdgcn_mfma_f32_16x16x16f16(fWc1[0], fb, cv[0], 0, 0, 0);
            float4_ t1v = __builtin_amdgcn_mfma_f32_16x16x16f16(fWc1[1], fb, cv[1], 0, 0, 0);
            float4_ t2v = __builtin_amdgcn_mfma_f32_16x16x16f16(fWc1[2], fb, cv[2], 0, 0, 0);
            float4_ t3v = __builtin_amdgcn_mfma_f32_16x16x16f16(fWc1[3], fb, cv[3], 0, 0, 0);
            uint2_ w;
            w.x = pkr(t0v.x, t0v.y); w.y = pkr(t0v.z, t0v.w); *(uint2_*)(hwp[p] + 0 * 256) = w;
            w.x = pkr(t1v.x, t1v.y); w.y = pkr(t1v.z, t1v.w); *(uint2_*)(hwp[p] + 1 * 256) = w;
            w.x = pkr(t2v.x, t2v.y); w.y = pkr(t2v.z, t2v.w); *(uint2_*)(hwp[p] + 2 * 256) = w;
            w.x = pkr(t3v.x, t3v.y); w.y = pkr(t3v.z, t3v.w); *(uint2_*)(hwp[p] + 3 * 256) = w;
        }

        // ---- FIN: read HC[p] -> C2 -> rgb logits ----
        #pragma unroll
        for (int p = 0; p < 2; ++p) {
            half8 cb0 = *(const half8*)(hrp[p] + 0);
            half8 cb1 = *(const half8*)(hrp[p] + 512);
            float4_ rgbp = __builtin_amdgcn_mfma_f32_16x16x32_f16(fWc2[0], cb0, binit, 0, 0, 0);
            rgbP[p] = __builtin_amdgcn_mfma_f32_16x16x32_f16(fWc2[1], cb1, rgbp, 0, 0, 0);
        }

        // ---- TAIL (q==0 lanes): sequential volume-rendering scan ----
        if (q == 0) {
            #pragma unroll
            for (int p = 0; p < 2; ++p) {
                float sigma = __expf(dhx[p] + s0b);
                float sd = sigma * deltaP[p] * dn;
                float e = __expf(-sd);
                float alpha = 1.0f - e;
                float w = trans * alpha;
                float rr = __builtin_amdgcn_rcpf(1.0f + __expf(-rgbP[p].x));
                float rg = __builtin_amdgcn_rcpf(1.0f + __expf(-rgbP[p].y));
                float rb = __builtin_amdgcn_rcpf(1.0f + __expf(-rgbP[p].z));
                cacc0 = fmaf(w, rr, cacc0);
                cacc1 = fmaf(w, rg, cacc1);
                cacc2 = fmaf(w, rb, cacc2);
                wacc += w;
                trans *= e;
                sdtot += sd;
            }
        }
    }

    if (q == 0) {
        sComb[wv][m][0] = sdtot;
        sComb[wv][m][1] = wacc;
        sComb[wv][m][2] = cacc0;
        sComb[wv][m][3] = cacc1;
        sComb[wv][m][4] = cacc2;
    }
    __syncthreads();

    // cross-segment combine
    if (tid < RPW) {
        float P = 1.0f, C0 = 0.0f, C1 = 0.0f, C2 = 0.0f, WS = 0.0f;
        #pragma unroll
        for (int s = 0; s < WAVES; ++s) {
            C0 = fmaf(P, sComb[s][tid][2], C0);
            C1 = fmaf(P, sComb[s][tid][3], C1);
            C2 = fmaf(P, sComb[s][tid][4], C2);
            WS = fmaf(P, sComb[s][tid][1], WS);
            P *= __expf(-sComb[s][tid][0]);
        }
        float act = active ? 1.0f : 0.0f;
        const int rg = blockIdx.x * RPW + tid;
        out[rg * 4 + 0] = C0 * act;
        out[rg * 4 + 1] = C1 * act;
        out[rg * 4 + 2] = C2 * act;
        out[rg * 4 + 3] = WS * act;
    }
}

extern "C" void kernel_launch(void* const* d_in, const int* in_sizes, int n_in,
                              void* d_out, int out_size, void* d_ws, size_t ws_size,
                              hipStream_t stream) {
    const float* rays_o = (const float*)d_in[0];
    const float* rays_d = (const float*)d_in[1];
    const float* tnoise = (const float*)d_in[2];
    const float* aabb   = (const float*)d_in[3];
    const float* W1  = (const float*)d_in[4];
    const float* b1  = (const float*)d_in[5];
    const float* W2  = (const float*)d_in[6];
    const float* b2  = (const float*)d_in[7];
    const float* Wc1 = (const float*)d_in[8];
    const float* bc1 = (const float*)d_in[9];
    const float* Wc2 = (const float*)d_in[10];
    const float* bc2 = (const float*)d_in[11];

    prep_weights<<<dim3(13), dim3(64), 0, stream>>>(W1, b1, W2, b2, Wc1, bc1, Wc2, bc2, d_ws);

    dim3 grid(N_RAYS / RPW);   // 1024 blocks
    dim3 block(WAVES * 64);    // 256 threads
    render_kernel<<<grid, block, 0, stream>>>(rays_o, rays_d, tnoise, aabb, d_ws,
                                              (float*)d_out);
}